// Round 11
// baseline (529.651 us; speedup 1.0000x reference)
//
#include <hip/hip_runtime.h>
#include <hip/hip_bf16.h>
#include <stdint.h>

// ---------------------------------------------------------------------------
// Problem constants
// ---------------------------------------------------------------------------
#define BB   4
#define SS   2048
#define DD   1024
#define NH   16
#define HDIM 64
#define FF   4096
#define NROW (BB*SS)          // 8192
#define LN_EPS 1e-4f

typedef __attribute__((ext_vector_type(8))) short  bf16x8;
typedef __attribute__((ext_vector_type(4))) float  f32x4;

__device__ __forceinline__ ushort f2bf(float f) {
    uint32_t u = __builtin_bit_cast(uint32_t, f);
    u += 0x7fff + ((u >> 16) & 1);
    return (ushort)(u >> 16);
}

__device__ __forceinline__ void load_lds16(const void* g, void* l) {
    __builtin_amdgcn_global_load_lds(
        (const __attribute__((address_space(1))) void*)g,
        (__attribute__((address_space(3))) void*)l, 16, 0, 0);
}

// ---------------------------------------------------------------------------
// fp32 -> bf16 convert, all six weights in one launch
// ---------------------------------------------------------------------------
__global__ __launch_bounds__(256) void cvt_all(
    const float* __restrict__ wq, const float* __restrict__ wk,
    const float* __restrict__ wv, const float* __restrict__ wu,
    const float* __restrict__ w1, const float* __restrict__ w2,
    ushort* __restrict__ wqkv, ushort* __restrict__ wu_b,
    ushort* __restrict__ w1_b, ushort* __restrict__ w2_b) {
    int i = blockIdx.x * 256 + threadIdx.x;   // float4 index
    const float* src; ushort* dst; int off;
    if (i < 262144)       { src = wq; dst = wqkv;           off = i; }
    else if (i < 524288)  { src = wk; dst = wqkv + 1048576; off = i - 262144; }
    else if (i < 786432)  { src = wv; dst = wqkv + 2097152; off = i - 524288; }
    else if (i < 1048576) { src = wu; dst = wu_b;           off = i - 786432; }
    else if (i < 2097152) { src = w1; dst = w1_b;           off = i - 1048576; }
    else                  { src = w2; dst = w2_b;           off = i - 2097152; }
    float4 v = ((const float4*)src)[off];
    ushort4 o;
    o.x = f2bf(v.x); o.y = f2bf(v.y); o.z = f2bf(v.z); o.w = f2bf(v.w);
    ((ushort4*)dst)[off] = o;
}

// ---------------------------------------------------------------------------
// LayerNorm (gamma=1, beta=0): fp32 in -> bf16 out.  One block per row of 1024.
// ---------------------------------------------------------------------------
__global__ __launch_bounds__(256) void ln_kernel(const float* __restrict__ x,
                                                 ushort* __restrict__ out) {
    int row = blockIdx.x;
    const float4* xr = (const float4*)(x + (size_t)row * DD);
    float4 v = xr[threadIdx.x];
    float s  = v.x + v.y + v.z + v.w;
    float ss = v.x*v.x + v.y*v.y + v.z*v.z + v.w*v.w;
    #pragma unroll
    for (int o = 32; o; o >>= 1) {
        s  += __shfl_xor(s, o);
        ss += __shfl_xor(ss, o);
    }
    __shared__ float ps[4], pss[4];
    if ((threadIdx.x & 63) == 0) { ps[threadIdx.x >> 6] = s; pss[threadIdx.x >> 6] = ss; }
    __syncthreads();
    s  = ps[0] + ps[1] + ps[2] + ps[3];
    ss = pss[0] + pss[1] + pss[2] + pss[3];
    float mean = s * (1.0f / DD);
    float var  = ss * (1.0f / DD) - mean * mean;
    float rstd = rsqrtf(var + LN_EPS);
    ushort4 o4;
    o4.x = f2bf((v.x - mean) * rstd);
    o4.y = f2bf((v.y - mean) * rstd);
    o4.z = f2bf((v.z - mean) * rstd);
    o4.w = f2bf((v.w - mean) * rstd);
    ((ushort4*)(out + (size_t)row * DD))[threadIdx.x] = o4;
}

// ---------------------------------------------------------------------------
// 128x128 bf16 GEMM (m97 structure) — used for proj / FFN2 (N=1024 shapes).
// ---------------------------------------------------------------------------
template<int MODE>
__global__ __launch_bounds__(256, 2) void gemm_bt(
    const ushort* __restrict__ A, const ushort* __restrict__ B,
    void* __restrict__ C, const float* __restrict__ bias,
    const float* __restrict__ resid, int M, int N, int K)
{
    __shared__ ushort As[128 * 32];
    __shared__ ushort Bs[128 * 32];

    int nn  = N >> 7;
    int nwg = (M >> 7) * nn;
    int bid = blockIdx.x;
    int wg  = (bid & 7) * (nwg >> 3) + (bid >> 3);   // XCD swizzle (nwg % 8 == 0)
    int tm = wg / nn, tn = wg % nn;
    size_t m0 = (size_t)tm * 128, n0 = (size_t)tn * 128;

    int tid = threadIdx.x, w = tid >> 6, lane = tid & 63;
    int lq = lane & 15, g = lane >> 4;
    int wr = w >> 1, wc = w & 1;

    f32x4 acc[4][4] = {};

    const int f0 = w * 1024 + lane * 8;   // element index base for staging

    for (int k0 = 0; k0 < K; k0 += 32) {
        __syncthreads();
        #pragma unroll
        for (int i = 0; i < 2; i++) {
            int f = f0 + i * 512;
            int r = f >> 5, c = f & 31;
            load_lds16(A + (m0 + r) * K + k0 + c, As + w * 1024 + i * 512);
            load_lds16(B + (n0 + r) * K + k0 + c, Bs + w * 1024 + i * 512);
        }
        __syncthreads();

        bf16x8 a[4], b[4];
        #pragma unroll
        for (int mt = 0; mt < 4; mt++)
            a[mt] = *(const bf16x8*)&As[(wr * 64 + mt * 16 + lq) * 32 + g * 8];
        #pragma unroll
        for (int nt = 0; nt < 4; nt++)
            b[nt] = *(const bf16x8*)&Bs[(wc * 64 + nt * 16 + lq) * 32 + g * 8];
        #pragma unroll
        for (int mt = 0; mt < 4; mt++)
            #pragma unroll
            for (int nt = 0; nt < 4; nt++)
                acc[mt][nt] = __builtin_amdgcn_mfma_f32_16x16x32_bf16(
                    a[mt], b[nt], acc[mt][nt], 0, 0, 0);
    }

    #pragma unroll
    for (int mt = 0; mt < 4; mt++) {
        #pragma unroll
        for (int nt = 0; nt < 4; nt++) {
            #pragma unroll
            for (int r = 0; r < 4; r++) {
                size_t row = m0 + wr * 64 + mt * 16 + g * 4 + r;
                size_t col = n0 + wc * 64 + nt * 16 + lq;
                float v = acc[mt][nt][r];
                if (MODE == 0) {
                    ((ushort*)C)[row * N + col] = f2bf(v);
                } else if (MODE == 1) {
                    ((float*)C)[row * N + col] = v + bias[col] + resid[row * N + col];
                } else {
                    float t = v + bias[col];
                    ((ushort*)C)[row * N + col] = f2bf(t > 0.f ? t : 0.f);
                }
            }
        }
    }
}

// ---------------------------------------------------------------------------
// 256x256 8-phase bf16 GEMM (unchanged from R10).
// ---------------------------------------------------------------------------
#define MFMA_BF16 __builtin_amdgcn_mfma_f32_16x16x32_bf16

template<int MODE>
__global__ __launch_bounds__(512, 2) void gemm256(
    const ushort* __restrict__ Aw, const ushort* __restrict__ Bw,
    void* __restrict__ C, const float* __restrict__ bias,
    int M, int N, int K)
{
    __shared__ ushort Ls[2][4][8192];   // [buf][slot][256*32]

    int nn  = N >> 8;
    int nwg = (M >> 8) * nn;
    int bid = blockIdx.x;
    int wg  = (bid & 7) * (nwg >> 3) + (bid >> 3);   // XCD swizzle (nwg % 8 == 0)
    int tm = wg / nn, tn = wg % nn;
    size_t m0 = (size_t)tm * 256, n0 = (size_t)tn * 256;

    int tid = threadIdx.x, wid = tid >> 6, lane = tid & 63;
    int lq = lane & 15, g = lane >> 4;
    int wr = wid >> 2, wc = wid & 3;

    f32x4 acc[8][4] = {};

#define STG(Tn, h, dbuf) do {                                                   \
    int ks_ = (h) >> 1;                                                         \
    const ushort* s_ = ((h) & 1) ? (Bw + n0 * (size_t)K) : (Aw + m0 * (size_t)K); \
    int kk_ = (Tn) * 64 + ks_ * 32;                                             \
    { int F_ = tid;       int r_ = F_ >> 2, c_ = F_ & 3;                        \
      load_lds16(s_ + (size_t)r_ * K + kk_ + ((c_ ^ ((r_ >> 1) & 3)) * 8),      \
                 &Ls[dbuf][h][(wid * 64) * 8]); }                               \
    { int F_ = 512 + tid; int r_ = F_ >> 2, c_ = F_ & 3;                        \
      load_lds16(s_ + (size_t)r_ * K + kk_ + ((c_ ^ ((r_ >> 1) & 3)) * 8),      \
                 &Ls[dbuf][h][(512 + wid * 64) * 8]); }                         \
  } while (0)

#define RD_A(mt, ks) (*(const bf16x8*)&Ls[cur][(ks)*2][((wr*128 + (mt)*16 + lq) * 32) + ((g ^ (((wr*128 + (mt)*16 + lq) >> 1) & 3)) * 8)])
#define RD_B(nt, ks) (*(const bf16x8*)&Ls[cur][(ks)*2+1][((wc*64 + (nt)*16 + lq) * 32) + ((g ^ (((wc*64 + (nt)*16 + lq) >> 1) & 3)) * 8)])

    // prologue: stage tile 0 fully; wait for its first two half-tiles
    STG(0, 0, 0); STG(0, 1, 0); STG(0, 2, 0); STG(0, 3, 0);
    asm volatile("s_waitcnt vmcnt(4)" ::: "memory");
    __builtin_amdgcn_sched_barrier(0);
    __builtin_amdgcn_s_barrier();

    int KT = K >> 6;
    #pragma unroll 1
    for (int T = 0; T < KT; ++T) {
        int cur = T & 1;
        bool st = (T + 1 < KT);
        bf16x8 aF[4], bF[4];

        // ---- phase 0: ks=0, mt 0-3 ----
        #pragma unroll
        for (int i = 0; i < 4; i++) aF[i] = RD_A(i, 0);
        #pragma unroll
        for (int i = 0; i < 4; i++) bF[i] = RD_B(i, 0);
        if (st) STG(T + 1, 0, cur ^ 1);
        __builtin_amdgcn_s_barrier();
        asm volatile("s_waitcnt lgkmcnt(0)" ::: "memory");
        __builtin_amdgcn_sched_barrier(0);
        __builtin_amdgcn_s_setprio(1);
        #pragma unroll
        for (int i = 0; i < 4; i++)
            #pragma unroll
            for (int nt = 0; nt < 4; nt++)
                acc[i][nt] = MFMA_BF16(aF[i], bF[nt], acc[i][nt], 0, 0, 0);
        __builtin_amdgcn_s_setprio(0);
        __builtin_amdgcn_s_barrier();

        // ---- phase 1: ks=0, mt 4-7 ----
        #pragma unroll
        for (int i = 0; i < 4; i++) aF[i] = RD_A(4 + i, 0);
        if (st) STG(T + 1, 1, cur ^ 1);
        __builtin_amdgcn_s_barrier();
        asm volatile("s_waitcnt lgkmcnt(0)" ::: "memory");
        __builtin_amdgcn_sched_barrier(0);
        __builtin_amdgcn_s_setprio(1);
        #pragma unroll
        for (int i = 0; i < 4; i++)
            #pragma unroll
            for (int nt = 0; nt < 4; nt++)
                acc[4 + i][nt] = MFMA_BF16(aF[i], bF[nt], acc[4 + i][nt], 0, 0, 0);
        __builtin_amdgcn_s_setprio(0);
        if (st) asm volatile("s_waitcnt vmcnt(4)" ::: "memory");
        else    asm volatile("s_waitcnt vmcnt(0)" ::: "memory");
        __builtin_amdgcn_sched_barrier(0);
        __builtin_amdgcn_s_barrier();

        // ---- phase 2: ks=1, mt 0-3 ----
        #pragma unroll
        for (int i = 0; i < 4; i++) aF[i] = RD_A(i, 1);
        #pragma unroll
        for (int i = 0; i < 4; i++) bF[i] = RD_B(i, 1);
        if (st) STG(T + 1, 2, cur ^ 1);
        __builtin_amdgcn_s_barrier();
        asm volatile("s_waitcnt lgkmcnt(0)" ::: "memory");
        __builtin_amdgcn_sched_barrier(0);
        __builtin_amdgcn_s_setprio(1);
        #pragma unroll
        for (int i = 0; i < 4; i++)
            #pragma unroll
            for (int nt = 0; nt < 4; nt++)
                acc[i][nt] = MFMA_BF16(aF[i], bF[nt], acc[i][nt], 0, 0, 0);
        __builtin_amdgcn_s_setprio(0);
        __builtin_amdgcn_s_barrier();

        // ---- phase 3: ks=1, mt 4-7 ----
        #pragma unroll
        for (int i = 0; i < 4; i++) aF[i] = RD_A(4 + i, 1);
        if (st) STG(T + 1, 3, cur ^ 1);
        __builtin_amdgcn_s_barrier();
        asm volatile("s_waitcnt lgkmcnt(0)" ::: "memory");
        __builtin_amdgcn_sched_barrier(0);
        __builtin_amdgcn_s_setprio(1);
        #pragma unroll
        for (int i = 0; i < 4; i++)
            #pragma unroll
            for (int nt = 0; nt < 4; nt++)
                acc[4 + i][nt] = MFMA_BF16(aF[i], bF[nt], acc[4 + i][nt], 0, 0, 0);
        __builtin_amdgcn_s_setprio(0);
        if (st) {
            asm volatile("s_waitcnt vmcnt(4)" ::: "memory");
            __builtin_amdgcn_sched_barrier(0);
        }
        __builtin_amdgcn_s_barrier();
    }

    // epilogue
    #pragma unroll
    for (int mt = 0; mt < 8; mt++) {
        #pragma unroll
        for (int nt = 0; nt < 4; nt++) {
            #pragma unroll
            for (int r = 0; r < 4; r++) {
                size_t row = m0 + wr * 128 + mt * 16 + g * 4 + r;
                size_t col = n0 + wc * 64 + nt * 16 + lq;
                float v = acc[mt][nt][r];
                if (MODE == 0) {
                    ((ushort*)C)[row * N + col] = f2bf(v);
                } else {
                    float t = v + bias[col];
                    ((ushort*)C)[row * N + col] = f2bf(t > 0.f ? t : 0.f);
                }
            }
        }
    }
#undef STG
#undef RD_A
#undef RD_B
}

// ---------------------------------------------------------------------------
// V transpose:  vt[bh][hd][s] = V[b,s,h,hd]   (V = qkv cols 2048..3071)
// ---------------------------------------------------------------------------
__global__ __launch_bounds__(256) void transpose_v(const ushort* __restrict__ qkv,
                                                   ushort* __restrict__ vt) {
    int idx = blockIdx.x * 256 + threadIdx.x;     // 64*8*2048 threads
    int s   = idx & (SS - 1);
    int cg  = (idx >> 11) & 7;
    int bh  = idx >> 14;
    int b = bh >> 4, h = bh & 15;
    bf16x8 v = *(const bf16x8*)(qkv + ((size_t)b * SS + s) * 3072 + 2048 + h * 64 + cg * 8);
    #pragma unroll
    for (int j = 0; j < 8; j++)
        vt[((size_t)bh * 64 + cg * 8 + j) * SS + s] = ((ushort*)&v)[j];
}

// ---------------------------------------------------------------------------
// Flash attention (causal), bf16 QKV.
// Grid = (bh=64, pr=16) for XCD K/V locality.  Pl stride 16 -> LDS 40960 B
// -> exactly 4 blocks/CU (was 3).  Defer-max + cvt_pk packing.
// ---------------------------------------------------------------------------
__global__ __launch_bounds__(256, 4) void attn_kernel(const ushort* __restrict__ qkv,
                                                      const ushort* __restrict__ vt,
                                                      ushort* __restrict__ ctx) {
    __shared__ ushort   Kl[2][64 * 64];
    __shared__ ushort   Vl[2][64 * 64];
    __shared__ uint32_t Pl[4][32 * 16];   // stride 16: 8 KB total

    int bh = blockIdx.x;                  // x-fastest -> XCD = bh & 7
    int pr = blockIdx.y;                  // 0..15 (q-tile pair)
    int b = bh >> 4, h = bh & 15;
    int tid = threadIdx.x, wid = tid >> 6, lane = tid & 63;
    int lq = lane & 15, g = lane >> 4;
    int sr = tid >> 3;
    int sc = (tid & 7) * 8;
    const float CE = 0.125f * 1.44269504f;

    const ushort* kbase = qkv + (size_t)b * SS * 3072 + 1024 + h * 64;
    const ushort* vbase = vt + (size_t)bh * 64 * SS;

    #define LOADSTAGE(T) do { int k0_ = (T) * 64;                                   \
        kr0 = *(const bf16x8*)(kbase + (size_t)(k0_ + sr) * 3072 + sc);             \
        kr1 = *(const bf16x8*)(kbase + (size_t)(k0_ + 32 + sr) * 3072 + sc);        \
        vr0 = *(const bf16x8*)(vbase + (size_t)sr * SS + k0_ + sc);                 \
        vr1 = *(const bf16x8*)(vbase + (size_t)(32 + sr) * SS + k0_ + sc); } while (0)

    #define WRITESTAGE(BUF) do {                                                    \
        int r0_ = sr, r1_ = 32 + sr, cc_ = sc >> 3;                                 \
        *(bf16x8*)&Kl[BUF][r0_ * 64 + ((cc_ ^ (r0_ & 7)) << 3)] = kr0;              \
        *(bf16x8*)&Kl[BUF][r1_ * 64 + ((cc_ ^ (r1_ & 7)) << 3)] = kr1;              \
        *(bf16x8*)&Vl[BUF][r0_ * 64 + ((cc_ ^ (r0_ & 7)) << 3)] = vr0;              \
        *(bf16x8*)&Vl[BUF][r1_ * 64 + ((cc_ ^ (r1_ & 7)) << 3)] = vr1; } while (0)

    #pragma unroll 1
    for (int half = 0; half < 2; half++) {
        int bx = half ? (31 - pr) : pr;
        int q0 = bx * 64;
        int qrow = q0 + wid * 16 + lq;
        const size_t qoff = ((size_t)b * SS + qrow) * 3072 + h * 64;
        bf16x8 qf0 = *(const bf16x8*)(qkv + qoff + g * 8);
        bf16x8 qf1 = *(const bf16x8*)(qkv + qoff + 32 + g * 8);

        f32x4 oacc[4] = {};
        float m = -1e30f, l = 0.f;
        int ntile = bx + 1;

        bf16x8 kr0, kr1, vr0, vr1;
        LOADSTAGE(0);
        __syncthreads();
        WRITESTAGE(0);
        int cur = 0;

        #pragma unroll 1
        for (int t = 0; t < ntile; ++t) {
            __syncthreads();
            if (t + 1 < ntile) LOADSTAGE(t + 1);

            f32x4 sa[4];
            __builtin_amdgcn_s_setprio(1);
            #pragma unroll
            for (int mt = 0; mt < 4; mt++) {
                int row = mt * 16 + lq;
                sa[mt] = f32x4{0.f, 0.f, 0.f, 0.f};
                bf16x8 a0 = *(const bf16x8*)&Kl[cur][row * 64 + ((g ^ (row & 7)) << 3)];
                sa[mt] = __builtin_amdgcn_mfma_f32_16x16x32_bf16(a0, qf0, sa[mt], 0, 0, 0);
                bf16x8 a1 = *(const bf16x8*)&Kl[cur][row * 64 + (((4 + g) ^ (row & 7)) << 3)];
                sa[mt] = __builtin_amdgcn_mfma_f32_16x16x32_bf16(a1, qf1, sa[mt], 0, 0, 0);
            }
            __builtin_amdgcn_s_setprio(0);

            float p[4][4];
            float tmax = -1e30f;
            if (t == ntile - 1) {
                int k0 = t * 64;
                #pragma unroll
                for (int mt = 0; mt < 4; mt++)
                    #pragma unroll
                    for (int r = 0; r < 4; r++) {
                        float s = sa[mt][r];
                        int key = k0 + mt * 16 + g * 4 + r;
                        if (key > qrow) s = -1e30f;
                        p[mt][r] = s;
                        tmax = fmaxf(tmax, s);
                    }
            } else {
                #pragma unroll
                for (int mt = 0; mt < 4; mt++)
                    #pragma unroll
                    for (int r = 0; r < 4; r++) {
                        float s = sa[mt][r];
                        p[mt][r] = s;
                        tmax = fmaxf(tmax, s);
                    }
            }
            tmax = fmaxf(tmax, __shfl_xor(tmax, 16));
            tmax = fmaxf(tmax, __shfl_xor(tmax, 32));

            // defer-max (T13): only rescale when tile max grows past m+8
            if (!__all(tmax - m <= 8.0f)) {
                float mnew  = fmaxf(m, tmax);
                float alpha = exp2f((m - mnew) * CE);
                l *= alpha;
                #pragma unroll
                for (int mt = 0; mt < 4; mt++)
                    #pragma unroll
                    for (int r = 0; r < 4; r++) oacc[mt][r] *= alpha;
                m = mnew;
            }

            float sum = 0.f;
            #pragma unroll
            for (int mt = 0; mt < 4; mt++)
                #pragma unroll
                for (int r = 0; r < 4; r++) {
                    float e = exp2f((p[mt][r] - m) * CE);
                    p[mt][r] = e;
                    sum += e;
                }
            sum += __shfl_xor(sum, 16);
            sum += __shfl_xor(sum, 32);
            l += sum;

            // pack P^T pairs via v_cvt_pk_bf16_f32
            #pragma unroll
            for (int mt = 0; mt < 4; mt++)
                #pragma unroll
                for (int w2 = 0; w2 < 2; w2++) {
                    uint32_t pk;
                    asm("v_cvt_pk_bf16_f32 %0, %1, %2"
                        : "=v"(pk) : "v"(p[mt][2 * w2]), "v"(p[mt][2 * w2 + 1]));
                    Pl[wid][(mt * 8 + g * 2 + w2) * 16 + lq] = pk;
                }

            __builtin_amdgcn_s_setprio(1);
            #pragma unroll
            for (int ks = 0; ks < 2; ks++) {
                union { uint32_t w[4]; bf16x8 v; } pb;
                #pragma unroll
                for (int c = 0; c < 4; c++)
                    pb.w[c] = Pl[wid][(ks * 16 + g * 4 + c) * 16 + lq];
                #pragma unroll
                for (int mt = 0; mt < 4; mt++) {
                    int row = mt * 16 + lq;
                    bf16x8 af = *(const bf16x8*)&Vl[cur][row * 64 + (((ks * 4 + g) ^ (row & 7)) << 3)];
                    oacc[mt] = __builtin_amdgcn_mfma_f32_16x16x32_bf16(af, pb.v, oacc[mt], 0, 0, 0);
                }
            }
            __builtin_amdgcn_s_setprio(0);

            if (t + 1 < ntile) WRITESTAGE(cur ^ 1);
            cur ^= 1;
        }

        float inv = 1.f / l;
        ushort* cb = ctx + ((size_t)b * SS + qrow) * DD + h * 64;
        #pragma unroll
        for (int mt = 0; mt < 4; mt++)
            #pragma unroll
            for (int r = 0; r < 4; r++)
                cb[mt * 16 + g * 4 + r] = f2bf(oacc[mt][r] * inv);
    }
    #undef LOADSTAGE
    #undef WRITESTAGE
}

// ---------------------------------------------------------------------------
// Launch
// ---------------------------------------------------------------------------
extern "C" void kernel_launch(void* const* d_in, const int* in_sizes, int n_in,
                              void* d_out, int out_size, void* d_ws, size_t ws_size,
                              hipStream_t stream) {
    const float* x  = (const float*)d_in[0];
    const float* wq = (const float*)d_in[1];
    const float* wk = (const float*)d_in[2];
    const float* wv = (const float*)d_in[3];
    const float* wu = (const float*)d_in[4];
    const float* bu = (const float*)d_in[5];
    const float* w1 = (const float*)d_in[6];
    const float* b1 = (const float*)d_in[7];
    const float* w2 = (const float*)d_in[8];
    const float* b2 = (const float*)d_in[9];
    float* out = (float*)d_out;

    // workspace layout (ushort units)
    ushort* ws = (ushort*)d_ws;
    size_t off = 0;
    ushort* wqkv = ws + off; off += (size_t)3072 * 1024;
    ushort* wu_b = ws + off; off += (size_t)1024 * 1024;
    ushort* w1_b = ws + off; off += (size_t)4096 * 1024;
    ushort* w2_b = ws + off; off += (size_t)4096 * 1024;
    ushort* lnb  = ws + off; off += (size_t)NROW * DD;
    float*  hbuf = (float*)(ws + off); off += (size_t)NROW * DD * 2;
    ushort* qkv  = ws + off;                       // region X
    ushort* ctx  = qkv + (size_t)NROW * 3072;
    ushort* gbuf = qkv;                            // aliases qkv+ctx (dead by then)
    off += (size_t)NROW * FF;
    ushort* vtb  = ws + off; off += (size_t)NROW * DD;
    (void)ws_size; (void)n_in; (void)in_sizes; (void)out_size;

    // weights -> bf16 (single fused launch)
    cvt_all<<<12288, 256, 0, stream>>>(wq, wk, wv, wu, w1, w2,
                                       wqkv, wu_b, w1_b, w2_b);

    // LN1
    ln_kernel<<<NROW, 256, 0, stream>>>(x, lnb);
    // QKV (256^2 8-phase)
    gemm256<0><<<(NROW / 256) * (3072 / 256), 512, 0, stream>>>(
        lnb, wqkv, qkv, nullptr, NROW, 3072, 1024);
    // V transpose
    transpose_v<<<4096, 256, 0, stream>>>(qkv, vtb);
    // attention (bh-major grid for XCD K/V locality)
    attn_kernel<<<dim3(BB * NH, 16), 256, 0, stream>>>(qkv, vtb, ctx);
    // out proj + residual -> h (fp32)
    gemm_bt<1><<<(NROW / 128) * (1024 / 128), 256, 0, stream>>>(
        ctx, wu_b, hbuf, bu, x, NROW, 1024, 1024);
    // LN2
    ln_kernel<<<NROW, 256, 0, stream>>>(hbuf, lnb);
    // FFN1 + ReLU (256^2 8-phase)
    gemm256<2><<<(NROW / 256) * (4096 / 256), 512, 0, stream>>>(
        lnb, w1_b, gbuf, b1, NROW, 4096, 1024);
    // FFN2 + residual -> out (fp32)
    gemm_bt<1><<<(NROW / 128) * (1024 / 128), 256, 0, stream>>>(
        gbuf, w2_b, out, b2, hbuf, NROW, 1024, 4096);
}

// Round 12
// 486.253 us; speedup vs baseline: 1.0893x; 1.0893x over previous
//
#include <hip/hip_runtime.h>
#include <hip/hip_bf16.h>
#include <stdint.h>

// ---------------------------------------------------------------------------
// Problem constants
// ---------------------------------------------------------------------------
#define BB   4
#define SS   2048
#define DD   1024
#define NH   16
#define HDIM 64
#define FF   4096
#define NROW (BB*SS)          // 8192
#define LN_EPS 1e-4f

typedef __attribute__((ext_vector_type(8))) short  bf16x8;
typedef __attribute__((ext_vector_type(4))) float  f32x4;

__device__ __forceinline__ ushort f2bf(float f) {
    uint32_t u = __builtin_bit_cast(uint32_t, f);
    u += 0x7fff + ((u >> 16) & 1);
    return (ushort)(u >> 16);
}

__device__ __forceinline__ void load_lds16(const void* g, void* l) {
    __builtin_amdgcn_global_load_lds(
        (const __attribute__((address_space(1))) void*)g,
        (__attribute__((address_space(3))) void*)l, 16, 0, 0);
}

// ---------------------------------------------------------------------------
// fp32 -> bf16 convert, all six weights in one launch
// ---------------------------------------------------------------------------
__global__ __launch_bounds__(256) void cvt_all(
    const float* __restrict__ wq, const float* __restrict__ wk,
    const float* __restrict__ wv, const float* __restrict__ wu,
    const float* __restrict__ w1, const float* __restrict__ w2,
    ushort* __restrict__ wqkv, ushort* __restrict__ wu_b,
    ushort* __restrict__ w1_b, ushort* __restrict__ w2_b) {
    int i = blockIdx.x * 256 + threadIdx.x;   // float4 index
    const float* src; ushort* dst; int off;
    if (i < 262144)       { src = wq; dst = wqkv;           off = i; }
    else if (i < 524288)  { src = wk; dst = wqkv + 1048576; off = i - 262144; }
    else if (i < 786432)  { src = wv; dst = wqkv + 2097152; off = i - 524288; }
    else if (i < 1048576) { src = wu; dst = wu_b;           off = i - 786432; }
    else if (i < 2097152) { src = w1; dst = w1_b;           off = i - 1048576; }
    else                  { src = w2; dst = w2_b;           off = i - 2097152; }
    float4 v = ((const float4*)src)[off];
    ushort4 o;
    o.x = f2bf(v.x); o.y = f2bf(v.y); o.z = f2bf(v.z); o.w = f2bf(v.w);
    ((ushort4*)dst)[off] = o;
}

// ---------------------------------------------------------------------------
// LayerNorm (gamma=1, beta=0): fp32 in -> bf16 out.  One block per row of 1024.
// ---------------------------------------------------------------------------
__global__ __launch_bounds__(256) void ln_kernel(const float* __restrict__ x,
                                                 ushort* __restrict__ out) {
    int row = blockIdx.x;
    const float4* xr = (const float4*)(x + (size_t)row * DD);
    float4 v = xr[threadIdx.x];
    float s  = v.x + v.y + v.z + v.w;
    float ss = v.x*v.x + v.y*v.y + v.z*v.z + v.w*v.w;
    #pragma unroll
    for (int o = 32; o; o >>= 1) {
        s  += __shfl_xor(s, o);
        ss += __shfl_xor(ss, o);
    }
    __shared__ float ps[4], pss[4];
    if ((threadIdx.x & 63) == 0) { ps[threadIdx.x >> 6] = s; pss[threadIdx.x >> 6] = ss; }
    __syncthreads();
    s  = ps[0] + ps[1] + ps[2] + ps[3];
    ss = pss[0] + pss[1] + pss[2] + pss[3];
    float mean = s * (1.0f / DD);
    float var  = ss * (1.0f / DD) - mean * mean;
    float rstd = rsqrtf(var + LN_EPS);
    ushort4 o4;
    o4.x = f2bf((v.x - mean) * rstd);
    o4.y = f2bf((v.y - mean) * rstd);
    o4.z = f2bf((v.z - mean) * rstd);
    o4.w = f2bf((v.w - mean) * rstd);
    ((ushort4*)(out + (size_t)row * DD))[threadIdx.x] = o4;
}

// ---------------------------------------------------------------------------
// 128x128 bf16 GEMM (m97 structure) + chunk-XOR LDS swizzle (both-sides):
// LDS[r][chunk] holds global chunk (chunk ^ ((r>>1)&3)); fragment reads use
// chunk = g ^ ((row>>1)&3).  Bank walk: 16 lanes/fixed-g spread over 8 banks
// x2 = 2-way (free), was 8-way (2.94x).  Used for proj / FFN2.
// ---------------------------------------------------------------------------
template<int MODE>
__global__ __launch_bounds__(256, 2) void gemm_bt(
    const ushort* __restrict__ A, const ushort* __restrict__ B,
    void* __restrict__ C, const float* __restrict__ bias,
    const float* __restrict__ resid, int M, int N, int K)
{
    __shared__ ushort As[128 * 32];
    __shared__ ushort Bs[128 * 32];

    int nn  = N >> 7;
    int nwg = (M >> 7) * nn;
    int bid = blockIdx.x;
    int wg  = (bid & 7) * (nwg >> 3) + (bid >> 3);   // XCD swizzle (nwg % 8 == 0)
    int tm = wg / nn, tn = wg % nn;
    size_t m0 = (size_t)tm * 128, n0 = (size_t)tn * 128;

    int tid = threadIdx.x, w = tid >> 6, lane = tid & 63;
    int lq = lane & 15, g = lane >> 4;
    int wr = w >> 1, wc = w & 1;

    f32x4 acc[4][4] = {};

    const int f0 = w * 1024 + lane * 8;   // element index base for staging

    for (int k0 = 0; k0 < K; k0 += 32) {
        __syncthreads();
        #pragma unroll
        for (int i = 0; i < 2; i++) {
            int f = f0 + i * 512;
            int r = f >> 5;
            int ch = ((f & 31) >> 3) ^ ((r >> 1) & 3);   // pre-swizzled source chunk
            load_lds16(A + (m0 + r) * K + k0 + ch * 8, As + w * 1024 + i * 512);
            load_lds16(B + (n0 + r) * K + k0 + ch * 8, Bs + w * 1024 + i * 512);
        }
        __syncthreads();

        bf16x8 a[4], b[4];
        #pragma unroll
        for (int mt = 0; mt < 4; mt++) {
            int row = wr * 64 + mt * 16 + lq;
            a[mt] = *(const bf16x8*)&As[row * 32 + ((g ^ ((row >> 1) & 3)) * 8)];
        }
        #pragma unroll
        for (int nt = 0; nt < 4; nt++) {
            int row = wc * 64 + nt * 16 + lq;
            b[nt] = *(const bf16x8*)&Bs[row * 32 + ((g ^ ((row >> 1) & 3)) * 8)];
        }
        #pragma unroll
        for (int mt = 0; mt < 4; mt++)
            #pragma unroll
            for (int nt = 0; nt < 4; nt++)
                acc[mt][nt] = __builtin_amdgcn_mfma_f32_16x16x32_bf16(
                    a[mt], b[nt], acc[mt][nt], 0, 0, 0);
    }

    #pragma unroll
    for (int mt = 0; mt < 4; mt++) {
        #pragma unroll
        for (int nt = 0; nt < 4; nt++) {
            #pragma unroll
            for (int r = 0; r < 4; r++) {
                size_t row = m0 + wr * 64 + mt * 16 + g * 4 + r;
                size_t col = n0 + wc * 64 + nt * 16 + lq;
                float v = acc[mt][nt][r];
                if (MODE == 0) {
                    ((ushort*)C)[row * N + col] = f2bf(v);
                } else if (MODE == 1) {
                    ((float*)C)[row * N + col] = v + bias[col] + resid[row * N + col];
                } else {
                    float t = v + bias[col];
                    ((ushort*)C)[row * N + col] = f2bf(t > 0.f ? t : 0.f);
                }
            }
        }
    }
}

// ---------------------------------------------------------------------------
// 256x256 8-phase bf16 GEMM (unchanged from R10/R11).
// ---------------------------------------------------------------------------
#define MFMA_BF16 __builtin_amdgcn_mfma_f32_16x16x32_bf16

template<int MODE>
__global__ __launch_bounds__(512, 2) void gemm256(
    const ushort* __restrict__ Aw, const ushort* __restrict__ Bw,
    void* __restrict__ C, const float* __restrict__ bias,
    int M, int N, int K)
{
    __shared__ ushort Ls[2][4][8192];   // [buf][slot][256*32]

    int nn  = N >> 8;
    int nwg = (M >> 8) * nn;
    int bid = blockIdx.x;
    int wg  = (bid & 7) * (nwg >> 3) + (bid >> 3);   // XCD swizzle (nwg % 8 == 0)
    int tm = wg / nn, tn = wg % nn;
    size_t m0 = (size_t)tm * 256, n0 = (size_t)tn * 256;

    int tid = threadIdx.x, wid = tid >> 6, lane = tid & 63;
    int lq = lane & 15, g = lane >> 4;
    int wr = wid >> 2, wc = wid & 3;

    f32x4 acc[8][4] = {};

#define STG(Tn, h, dbuf) do {                                                   \
    int ks_ = (h) >> 1;                                                         \
    const ushort* s_ = ((h) & 1) ? (Bw + n0 * (size_t)K) : (Aw + m0 * (size_t)K); \
    int kk_ = (Tn) * 64 + ks_ * 32;                                             \
    { int F_ = tid;       int r_ = F_ >> 2, c_ = F_ & 3;                        \
      load_lds16(s_ + (size_t)r_ * K + kk_ + ((c_ ^ ((r_ >> 1) & 3)) * 8),      \
                 &Ls[dbuf][h][(wid * 64) * 8]); }                               \
    { int F_ = 512 + tid; int r_ = F_ >> 2, c_ = F_ & 3;                        \
      load_lds16(s_ + (size_t)r_ * K + kk_ + ((c_ ^ ((r_ >> 1) & 3)) * 8),      \
                 &Ls[dbuf][h][(512 + wid * 64) * 8]); }                         \
  } while (0)

#define RD_A(mt, ks) (*(const bf16x8*)&Ls[cur][(ks)*2][((wr*128 + (mt)*16 + lq) * 32) + ((g ^ (((wr*128 + (mt)*16 + lq) >> 1) & 3)) * 8)])
#define RD_B(nt, ks) (*(const bf16x8*)&Ls[cur][(ks)*2+1][((wc*64 + (nt)*16 + lq) * 32) + ((g ^ (((wc*64 + (nt)*16 + lq) >> 1) & 3)) * 8)])

    // prologue: stage tile 0 fully; wait for its first two half-tiles
    STG(0, 0, 0); STG(0, 1, 0); STG(0, 2, 0); STG(0, 3, 0);
    asm volatile("s_waitcnt vmcnt(4)" ::: "memory");
    __builtin_amdgcn_sched_barrier(0);
    __builtin_amdgcn_s_barrier();

    int KT = K >> 6;
    #pragma unroll 1
    for (int T = 0; T < KT; ++T) {
        int cur = T & 1;
        bool st = (T + 1 < KT);
        bf16x8 aF[4], bF[4];

        // ---- phase 0: ks=0, mt 0-3 ----
        #pragma unroll
        for (int i = 0; i < 4; i++) aF[i] = RD_A(i, 0);
        #pragma unroll
        for (int i = 0; i < 4; i++) bF[i] = RD_B(i, 0);
        if (st) STG(T + 1, 0, cur ^ 1);
        __builtin_amdgcn_s_barrier();
        asm volatile("s_waitcnt lgkmcnt(0)" ::: "memory");
        __builtin_amdgcn_sched_barrier(0);
        __builtin_amdgcn_s_setprio(1);
        #pragma unroll
        for (int i = 0; i < 4; i++)
            #pragma unroll
            for (int nt = 0; nt < 4; nt++)
                acc[i][nt] = MFMA_BF16(aF[i], bF[nt], acc[i][nt], 0, 0, 0);
        __builtin_amdgcn_s_setprio(0);
        __builtin_amdgcn_s_barrier();

        // ---- phase 1: ks=0, mt 4-7 ----
        #pragma unroll
        for (int i = 0; i < 4; i++) aF[i] = RD_A(4 + i, 0);
        if (st) STG(T + 1, 1, cur ^ 1);
        __builtin_amdgcn_s_barrier();
        asm volatile("s_waitcnt lgkmcnt(0)" ::: "memory");
        __builtin_amdgcn_sched_barrier(0);
        __builtin_amdgcn_s_setprio(1);
        #pragma unroll
        for (int i = 0; i < 4; i++)
            #pragma unroll
            for (int nt = 0; nt < 4; nt++)
                acc[4 + i][nt] = MFMA_BF16(aF[i], bF[nt], acc[4 + i][nt], 0, 0, 0);
        __builtin_amdgcn_s_setprio(0);
        if (st) asm volatile("s_waitcnt vmcnt(4)" ::: "memory");
        else    asm volatile("s_waitcnt vmcnt(0)" ::: "memory");
        __builtin_amdgcn_sched_barrier(0);
        __builtin_amdgcn_s_barrier();

        // ---- phase 2: ks=1, mt 0-3 ----
        #pragma unroll
        for (int i = 0; i < 4; i++) aF[i] = RD_A(i, 1);
        #pragma unroll
        for (int i = 0; i < 4; i++) bF[i] = RD_B(i, 1);
        if (st) STG(T + 1, 2, cur ^ 1);
        __builtin_amdgcn_s_barrier();
        asm volatile("s_waitcnt lgkmcnt(0)" ::: "memory");
        __builtin_amdgcn_sched_barrier(0);
        __builtin_amdgcn_s_setprio(1);
        #pragma unroll
        for (int i = 0; i < 4; i++)
            #pragma unroll
            for (int nt = 0; nt < 4; nt++)
                acc[i][nt] = MFMA_BF16(aF[i], bF[nt], acc[i][nt], 0, 0, 0);
        __builtin_amdgcn_s_setprio(0);
        __builtin_amdgcn_s_barrier();

        // ---- phase 3: ks=1, mt 4-7 ----
        #pragma unroll
        for (int i = 0; i < 4; i++) aF[i] = RD_A(4 + i, 1);
        if (st) STG(T + 1, 3, cur ^ 1);
        __builtin_amdgcn_s_barrier();
        asm volatile("s_waitcnt lgkmcnt(0)" ::: "memory");
        __builtin_amdgcn_sched_barrier(0);
        __builtin_amdgcn_s_setprio(1);
        #pragma unroll
        for (int i = 0; i < 4; i++)
            #pragma unroll
            for (int nt = 0; nt < 4; nt++)
                acc[4 + i][nt] = MFMA_BF16(aF[i], bF[nt], acc[4 + i][nt], 0, 0, 0);
        __builtin_amdgcn_s_setprio(0);
        if (st) {
            asm volatile("s_waitcnt vmcnt(4)" ::: "memory");
            __builtin_amdgcn_sched_barrier(0);
        }
        __builtin_amdgcn_s_barrier();
    }

    // epilogue
    #pragma unroll
    for (int mt = 0; mt < 8; mt++) {
        #pragma unroll
        for (int nt = 0; nt < 4; nt++) {
            #pragma unroll
            for (int r = 0; r < 4; r++) {
                size_t row = m0 + wr * 128 + mt * 16 + g * 4 + r;
                size_t col = n0 + wc * 64 + nt * 16 + lq;
                float v = acc[mt][nt][r];
                if (MODE == 0) {
                    ((ushort*)C)[row * N + col] = f2bf(v);
                } else {
                    float t = v + bias[col];
                    ((ushort*)C)[row * N + col] = f2bf(t > 0.f ? t : 0.f);
                }
            }
        }
    }
#undef STG
#undef RD_A
#undef RD_B
}

// ---------------------------------------------------------------------------
// V transpose:  vt[bh][hd][s] = V[b,s,h,hd]   (V = qkv cols 2048..3071)
// ---------------------------------------------------------------------------
__global__ __launch_bounds__(256) void transpose_v(const ushort* __restrict__ qkv,
                                                   ushort* __restrict__ vt) {
    int idx = blockIdx.x * 256 + threadIdx.x;     // 64*8*2048 threads
    int s   = idx & (SS - 1);
    int cg  = (idx >> 11) & 7;
    int bh  = idx >> 14;
    int b = bh >> 4, h = bh & 15;
    bf16x8 v = *(const bf16x8*)(qkv + ((size_t)b * SS + s) * 3072 + 2048 + h * 64 + cg * 8);
    #pragma unroll
    for (int j = 0; j < 8; j++)
        vt[((size_t)bh * 64 + cg * 8 + j) * SS + s] = ((ushort*)&v)[j];
}

// ---------------------------------------------------------------------------
// Flash attention (causal), bf16 QKV.  (unchanged from R11)
// ---------------------------------------------------------------------------
__global__ __launch_bounds__(256, 4) void attn_kernel(const ushort* __restrict__ qkv,
                                                      const ushort* __restrict__ vt,
                                                      ushort* __restrict__ ctx) {
    __shared__ ushort   Kl[2][64 * 64];
    __shared__ ushort   Vl[2][64 * 64];
    __shared__ uint32_t Pl[4][32 * 16];   // stride 16: 8 KB total

    int bh = blockIdx.x;                  // x-fastest -> XCD = bh & 7
    int pr = blockIdx.y;                  // 0..15 (q-tile pair)
    int b = bh >> 4, h = bh & 15;
    int tid = threadIdx.x, wid = tid >> 6, lane = tid & 63;
    int lq = lane & 15, g = lane >> 4;
    int sr = tid >> 3;
    int sc = (tid & 7) * 8;
    const float CE = 0.125f * 1.44269504f;

    const ushort* kbase = qkv + (size_t)b * SS * 3072 + 1024 + h * 64;
    const ushort* vbase = vt + (size_t)bh * 64 * SS;

    #define LOADSTAGE(T) do { int k0_ = (T) * 64;                                   \
        kr0 = *(const bf16x8*)(kbase + (size_t)(k0_ + sr) * 3072 + sc);             \
        kr1 = *(const bf16x8*)(kbase + (size_t)(k0_ + 32 + sr) * 3072 + sc);        \
        vr0 = *(const bf16x8*)(vbase + (size_t)sr * SS + k0_ + sc);                 \
        vr1 = *(const bf16x8*)(vbase + (size_t)(32 + sr) * SS + k0_ + sc); } while (0)

    #define WRITESTAGE(BUF) do {                                                    \
        int r0_ = sr, r1_ = 32 + sr, cc_ = sc >> 3;                                 \
        *(bf16x8*)&Kl[BUF][r0_ * 64 + ((cc_ ^ (r0_ & 7)) << 3)] = kr0;              \
        *(bf16x8*)&Kl[BUF][r1_ * 64 + ((cc_ ^ (r1_ & 7)) << 3)] = kr1;              \
        *(bf16x8*)&Vl[BUF][r0_ * 64 + ((cc_ ^ (r0_ & 7)) << 3)] = vr0;              \
        *(bf16x8*)&Vl[BUF][r1_ * 64 + ((cc_ ^ (r1_ & 7)) << 3)] = vr1; } while (0)

    #pragma unroll 1
    for (int half = 0; half < 2; half++) {
        int bx = half ? (31 - pr) : pr;
        int q0 = bx * 64;
        int qrow = q0 + wid * 16 + lq;
        const size_t qoff = ((size_t)b * SS + qrow) * 3072 + h * 64;
        bf16x8 qf0 = *(const bf16x8*)(qkv + qoff + g * 8);
        bf16x8 qf1 = *(const bf16x8*)(qkv + qoff + 32 + g * 8);

        f32x4 oacc[4] = {};
        float m = -1e30f, l = 0.f;
        int ntile = bx + 1;

        bf16x8 kr0, kr1, vr0, vr1;
        LOADSTAGE(0);
        __syncthreads();
        WRITESTAGE(0);
        int cur = 0;

        #pragma unroll 1
        for (int t = 0; t < ntile; ++t) {
            __syncthreads();
            if (t + 1 < ntile) LOADSTAGE(t + 1);

            f32x4 sa[4];
            __builtin_amdgcn_s_setprio(1);
            #pragma unroll
            for (int mt = 0; mt < 4; mt++) {
                int row = mt * 16 + lq;
                sa[mt] = f32x4{0.f, 0.f, 0.f, 0.f};
                bf16x8 a0 = *(const bf16x8*)&Kl[cur][row * 64 + ((g ^ (row & 7)) << 3)];
                sa[mt] = __builtin_amdgcn_mfma_f32_16x16x32_bf16(a0, qf0, sa[mt], 0, 0, 0);
                bf16x8 a1 = *(const bf16x8*)&Kl[cur][row * 64 + (((4 + g) ^ (row & 7)) << 3)];
                sa[mt] = __builtin_amdgcn_mfma_f32_16x16x32_bf16(a1, qf1, sa[mt], 0, 0, 0);
            }
            __builtin_amdgcn_s_setprio(0);

            float p[4][4];
            float tmax = -1e30f;
            if (t == ntile - 1) {
                int k0 = t * 64;
                #pragma unroll
                for (int mt = 0; mt < 4; mt++)
                    #pragma unroll
                    for (int r = 0; r < 4; r++) {
                        float s = sa[mt][r];
                        int key = k0 + mt * 16 + g * 4 + r;
                        if (key > qrow) s = -1e30f;
                        p[mt][r] = s;
                        tmax = fmaxf(tmax, s);
                    }
            } else {
                #pragma unroll
                for (int mt = 0; mt < 4; mt++)
                    #pragma unroll
                    for (int r = 0; r < 4; r++) {
                        float s = sa[mt][r];
                        p[mt][r] = s;
                        tmax = fmaxf(tmax, s);
                    }
            }
            tmax = fmaxf(tmax, __shfl_xor(tmax, 16));
            tmax = fmaxf(tmax, __shfl_xor(tmax, 32));

            // defer-max (T13): only rescale when tile max grows past m+8
            if (!__all(tmax - m <= 8.0f)) {
                float mnew  = fmaxf(m, tmax);
                float alpha = exp2f((m - mnew) * CE);
                l *= alpha;
                #pragma unroll
                for (int mt = 0; mt < 4; mt++)
                    #pragma unroll
                    for (int r = 0; r < 4; r++) oacc[mt][r] *= alpha;
                m = mnew;
            }

            float sum = 0.f;
            #pragma unroll
            for (int mt = 0; mt < 4; mt++)
                #pragma unroll
                for (int r = 0; r < 4; r++) {
                    float e = exp2f((p[mt][r] - m) * CE);
                    p[mt][r] = e;
                    sum += e;
                }
            sum += __shfl_xor(sum, 16);
            sum += __shfl_xor(sum, 32);
            l += sum;

            // pack P^T pairs via v_cvt_pk_bf16_f32
            #pragma unroll
            for (int mt = 0; mt < 4; mt++)
                #pragma unroll
                for (int w2 = 0; w2 < 2; w2++) {
                    uint32_t pk;
                    asm("v_cvt_pk_bf16_f32 %0, %1, %2"
                        : "=v"(pk) : "v"(p[mt][2 * w2]), "v"(p[mt][2 * w2 + 1]));
                    Pl[wid][(mt * 8 + g * 2 + w2) * 16 + lq] = pk;
                }

            __builtin_amdgcn_s_setprio(1);
            #pragma unroll
            for (int ks = 0; ks < 2; ks++) {
                union { uint32_t w[4]; bf16x8 v; } pb;
                #pragma unroll
                for (int c = 0; c < 4; c++)
                    pb.w[c] = Pl[wid][(ks * 16 + g * 4 + c) * 16 + lq];
                #pragma unroll
                for (int mt = 0; mt < 4; mt++) {
                    int row = mt * 16 + lq;
                    bf16x8 af = *(const bf16x8*)&Vl[cur][row * 64 + (((ks * 4 + g) ^ (row & 7)) << 3)];
                    oacc[mt] = __builtin_amdgcn_mfma_f32_16x16x32_bf16(af, pb.v, oacc[mt], 0, 0, 0);
                }
            }
            __builtin_amdgcn_s_setprio(0);

            if (t + 1 < ntile) WRITESTAGE(cur ^ 1);
            cur ^= 1;
        }

        float inv = 1.f / l;
        ushort* cb = ctx + ((size_t)b * SS + qrow) * DD + h * 64;
        #pragma unroll
        for (int mt = 0; mt < 4; mt++)
            #pragma unroll
            for (int r = 0; r < 4; r++)
                cb[mt * 16 + g * 4 + r] = f2bf(oacc[mt][r] * inv);
    }
    #undef LOADSTAGE
    #undef WRITESTAGE
}

// ---------------------------------------------------------------------------
// Launch
// ---------------------------------------------------------------------------
extern "C" void kernel_launch(void* const* d_in, const int* in_sizes, int n_in,
                              void* d_out, int out_size, void* d_ws, size_t ws_size,
                              hipStream_t stream) {
    const float* x  = (const float*)d_in[0];
    const float* wq = (const float*)d_in[1];
    const float* wk = (const float*)d_in[2];
    const float* wv = (const float*)d_in[3];
    const float* wu = (const float*)d_in[4];
    const float* bu = (const float*)d_in[5];
    const float* w1 = (const float*)d_in[6];
    const float* b1 = (const float*)d_in[7];
    const float* w2 = (const float*)d_in[8];
    const float* b2 = (const float*)d_in[9];
    float* out = (float*)d_out;

    // workspace layout (ushort units)
    ushort* ws = (ushort*)d_ws;
    size_t off = 0;
    ushort* wqkv = ws + off; off += (size_t)3072 * 1024;
    ushort* wu_b = ws + off; off += (size_t)1024 * 1024;
    ushort* w1_b = ws + off; off += (size_t)4096 * 1024;
    ushort* w2_b = ws + off; off += (size_t)4096 * 1024;
    ushort* lnb  = ws + off; off += (size_t)NROW * DD;
    float*  hbuf = (float*)(ws + off); off += (size_t)NROW * DD * 2;
    ushort* qkv  = ws + off;                       // region X
    ushort* ctx  = qkv + (size_t)NROW * 3072;
    ushort* gbuf = qkv;                            // aliases qkv+ctx (dead by then)
    off += (size_t)NROW * FF;
    ushort* vtb  = ws + off; off += (size_t)NROW * DD;
    (void)ws_size; (void)n_in; (void)in_sizes; (void)out_size;

    // weights -> bf16 (single fused launch)
    cvt_all<<<12288, 256, 0, stream>>>(wq, wk, wv, wu, w1, w2,
                                       wqkv, wu_b, w1_b, w2_b);

    // LN1
    ln_kernel<<<NROW, 256, 0, stream>>>(x, lnb);
    // QKV (256^2 8-phase)
    gemm256<0><<<(NROW / 256) * (3072 / 256), 512, 0, stream>>>(
        lnb, wqkv, qkv, nullptr, NROW, 3072, 1024);
    // V transpose
    transpose_v<<<4096, 256, 0, stream>>>(qkv, vtb);
    // attention (bh-major grid for XCD K/V locality)
    attn_kernel<<<dim3(BB * NH, 16), 256, 0, stream>>>(qkv, vtb, ctx);
    // out proj + residual -> h (fp32)
    gemm_bt<1><<<(NROW / 128) * (1024 / 128), 256, 0, stream>>>(
        ctx, wu_b, hbuf, bu, x, NROW, 1024, 1024);
    // LN2
    ln_kernel<<<NROW, 256, 0, stream>>>(hbuf, lnb);
    // FFN1 + ReLU (256^2 8-phase)
    gemm256<2><<<(NROW / 256) * (4096 / 256), 512, 0, stream>>>(
        lnb, w1_b, gbuf, b1, NROW, 4096, 1024);
    // FFN2 + residual -> out (fp32)
    gemm_bt<1><<<(NROW / 128) * (1024 / 128), 256, 0, stream>>>(
        gbuf, w2_b, out, b2, hbuf, NROW, 1024, 4096);
}